// Round 17
// baseline (216.459 us; speedup 1.0000x reference)
//
#include <hip/hip_runtime.h>
#include <hip/hip_fp16.h>

// Problem constants (fixed by the reference)
constexpr int NN  = 50000;   // nodes
constexpr int NNZ = 800000;  // edges per relation
constexpr int RR  = 3;       // relations
constexpr int D   = 128;     // feature dim (in == out)
constexpr int RN  = RR * NN; // fine buckets (150000)
constexpr int NE  = RR * NNZ;
constexpr int PART = 256;    // coarse partitions (1 sort block per CU)
constexpr int PSZ  = (RN + PART - 1) / PART;  // 586 buckets per partition
constexpr int CAP  = 10240;  // partition capacity (mean 9375, sd ~97)
constexpr int EPB  = 2048;   // edges per split block
constexpr int NPB  = 32;     // nodes per gather_gemm block
constexpr float EPS = 1e-6f;

constexpr int NB_SPLIT = (NE + EPB - 1) / EPB;        // 1172
constexpr int NB_XH    = (NN * 64 + 255) / 256;       // 12500
constexpr int NB_WT    = 256;                         // 512*128 / 256

using bf16x8 = __attribute__((ext_vector_type(8))) __bf16;
using f32x4  = __attribute__((ext_vector_type(4))) float;

// RNE f32 -> bf16 packing helpers (NaN not possible here)
__device__ __forceinline__ unsigned pack_bf2(float a, float b) {
  unsigned ua = __float_as_uint(a); ua = (ua + (0x7FFFu + ((ua >> 16) & 1))) >> 16;
  unsigned ub = __float_as_uint(b); ub = (ub + (0x7FFFu + ((ub >> 16) & 1))) >> 16;
  return ua | (ub << 16);
}
__device__ __forceinline__ unsigned bf16_lo(float a) {
  unsigned ua = __float_as_uint(a);
  return (ua + (0x7FFFu + ((ua >> 16) & 1))) >> 16;
}

__device__ __forceinline__ float val16(unsigned u) {
  return __half2float(__ushort_as_half((unsigned short)(u & 0xFFFFu)));
}

// fp16-pair FMA into f32 accumulators
#define ACC2(accA, accB, word, vv) {                                   \
    __half2 _h = __builtin_bit_cast(__half2, (word));                  \
    accA = __builtin_fmaf(__half2float(_h.x), (vv), accA);             \
    accB = __builtin_fmaf(__half2float(_h.y), (vv), accB); }

// ---------------------------------------------------------------------------
// K1 "prep": compact multisplit + table builds fused (R15 structure).
// ---------------------------------------------------------------------------
__global__ __launch_bounds__(256) void prep(
    const int*   __restrict__ rows,
    const int*   __restrict__ cols,
    const float* __restrict__ vals,
    const float* __restrict__ x,
    const float* __restrict__ w,     // [384][128]
    const float* __restrict__ shw,   // [128][128]
    int*   __restrict__ pcur,        // [PART]
    uint2* __restrict__ pedges,      // [PART*CAP]
    unsigned* __restrict__ xh,       // [NN*64] half2
    unsigned short* __restrict__ WT) { // bf16 [128][512]
  __shared__ uint2 sbuf[EPB];        // 16 KB compact staging
  __shared__ int lcur[PART];
  __shared__ int lstart[PART];
  __shared__ int lbase[PART];
  __shared__ int sdata[256];
  int blk = blockIdx.x;
  int t = threadIdx.x;

  if (blk >= NB_SPLIT) {                     // ---- copy paths (no LDS use)
    int b2 = blk - NB_SPLIT;
    if (b2 < NB_XH) {                        // build_xh
      int i = b2 * 256 + t;
      float2 v = ((const float2*)x)[i];
      xh[i] = __builtin_bit_cast(unsigned, __floats2half2_rn(v.x, v.y));
    } else {                                 // build_wt
      int idx = (b2 - NB_XH) * 256 + t;      // 0..65535
      int k   = idx >> 7;
      int col = idx & 127;
      float v = (k < 384) ? w[k * 128 + col] : shw[(k - 384) * 128 + col];
      WT[col * 512 + k] = (unsigned short)bf16_lo(v);
    }
    return;
  }

  // ---- multisplit path
  lcur[t] = 0;
  __syncthreads();

  int e0 = blk * EPB;
  int nvalid = min(EPB, NE - e0);
  constexpr int EPT = EPB / 256;     // 8 edges per thread
  int ebk[EPT]; unsigned epay[EPT];
  #pragma unroll
  for (int j = 0; j < EPT; j++) {
    int e = e0 + j * 256 + t;
    if (e < NE) {
      int r = (e >= 2 * NNZ) ? 2 : (e >= NNZ ? 1 : 0);
      int b = r * NN + rows[e];
      ebk[j] = b;
      epay[j] = ((unsigned)cols[e] << 16) |
                (unsigned)__half_as_ushort(__float2half_rn(vals[e]));
      atomicAdd(&lcur[b / PSZ], 1);
    } else {
      ebk[j] = -1;
    }
  }
  __syncthreads();

  int cnt = lcur[t];
  sdata[t] = cnt;
  __syncthreads();
  #pragma unroll
  for (int step = 1; step < 256; step <<= 1) {
    int v = (t >= step) ? sdata[t - step] : 0;
    __syncthreads();
    sdata[t] += v;
    __syncthreads();
  }
  int excl = sdata[t] - cnt;
  lstart[t] = excl;
  lbase[t] = atomicAdd(&pcur[t], cnt);
  __syncthreads();
  lcur[t] = excl;
  __syncthreads();

  #pragma unroll
  for (int j = 0; j < EPT; j++) {
    if (ebk[j] >= 0) {
      int pos = atomicAdd(&lcur[ebk[j] / PSZ], 1);
      sbuf[pos] = make_uint2((unsigned)ebk[j], epay[j]);
    }
  }
  __syncthreads();

  for (int i = t; i < nvalid; i += 256) {
    uint2 ed = sbuf[i];
    int p = (int)(ed.x / PSZ);
    pedges[(size_t)p * CAP + lbase[p] + (i - lstart[p])] = ed;
  }
}

// ---------------------------------------------------------------------------
// K2: per-partition LDS counting sort (256 blocks x 512 threads).
// ---------------------------------------------------------------------------
__global__ __launch_bounds__(512) void sort_part(
    const uint2* __restrict__ pedges,
    const int*   __restrict__ pcur,
    int* __restrict__ off,
    unsigned* __restrict__ epack) {
  __shared__ int sc[PSZ];
  __shared__ int sdata[512];
  int p = blockIdx.x;
  int t = threadIdx.x;
  int bb = p * PSZ;
  int nbuck = min(PSZ, RN - bb);
  int n = pcur[p];
  const uint2* src = pedges + (size_t)p * CAP;

  sdata[t] = (t < p && t < PART) ? pcur[t] : 0;
  __syncthreads();
  #pragma unroll
  for (int step = 256; step >= 1; step >>= 1) {
    if (t < step) sdata[t] += sdata[t + step];
    __syncthreads();
  }
  int gbase = sdata[0];
  __syncthreads();
  if (p == 0 && t == 0) off[RN] = NE;

  for (int i = t; i < nbuck; i += 512) sc[i] = 0;
  __syncthreads();
  for (int i = t; i < n; i += 512)
    atomicAdd(&sc[src[i].x - bb], 1);
  __syncthreads();

  constexpr int PER = (PSZ + 511) / 512;    // 2
  int lo = t * PER, hi = min(lo + PER, nbuck);
  int s = 0;
  for (int i = lo; i < hi; i++) s += sc[i];
  sdata[t] = s;
  __syncthreads();
  #pragma unroll
  for (int step = 1; step < 512; step <<= 1) {
    int v = (t >= step) ? sdata[t - step] : 0;
    __syncthreads();
    sdata[t] += v;
    __syncthreads();
  }
  int run = gbase + sdata[t] - s;
  for (int i = lo; i < hi; i++) {
    int c = sc[i];
    sc[i] = run;
    off[bb + i] = run;
    run += c;
  }
  __syncthreads();

  for (int i = t; i < n; i += 512) {
    uint2 ed = src[i];
    int pos = atomicAdd(&sc[ed.x - bb], 1);
    epack[pos] = ed.y;
  }
}

// ---------------------------------------------------------------------------
// K3: FUSED gather+LN+GEMM. Block = 32 nodes (4 waves x 8 nodes seq).
// Phase 1 (gather): R11 body per node; bf16 A-row (3 slabs + LN) written to
// a 32KB LDS tile, slot-XOR swizzled: elem (r*128+q*8) -> slot (r*16+q),
// stored at slot^(row&7). Phase 2 (mini-GEMM): [32x512]@WT[512x128] via
// mfma_16x16x32; A-frags from LDS (read slot kk*4+ks, same XOR), B-frags
// streamed from L2-hot WT (same byte layout as the old verified gemm).
// Kills the 51MB A-matrix round-trip and the separate gemm dispatch.
// ---------------------------------------------------------------------------
__global__ __launch_bounds__(256) void gather_gemm(
    const unsigned* __restrict__ xh,    // [NN][64] half2
    const unsigned* __restrict__ epack, // [NE] col16|fp16val, bucket-sorted
    const int*      __restrict__ off,   // [RN+1]
    const float* __restrict__ gamma,
    const float* __restrict__ beta,
    const char*  __restrict__ WTb,      // bf16 [128][512] as bytes
    const float* __restrict__ bias,     // [128]
    float* __restrict__ out) {          // [NN][128]
  __shared__ __align__(16) char A_lds[NPB * 1024];   // 32 KB
  int n0   = blockIdx.x * NPB;
  int t    = threadIdx.x;
  int wv   = t >> 6;
  int lane = t & 63;
  int g  = lane >> 4;        // edge subgroup 0..3
  int q  = lane & 15;        // dim slice: dims 8q..8q+7
  const unsigned* xq = xh + q * 4;

  // ---- Phase 1: gather 8 nodes per wave ----
  for (int i = 0; i < 8; i++) {
    int row  = wv * 8 + i;
    int node = n0 + row;
    if (node >= NN) {               // zero tail rows so MFMA reads are clean
      uint4 z = make_uint4(0, 0, 0, 0);
      *(uint4*)(A_lds + row * 1024 + lane * 16) = z;
      continue;
    }
    float l0=0,l1=0,l2=0,l3=0,l4=0,l5=0,l6=0,l7=0;

    #pragma unroll
    for (int r = 0; r < RR; r++) {
      int b = r * NN + node;
      int s = off[b], e2 = off[b + 1];
      float a0=0,a1=0,a2=0,a3=0,a4=0,a5=0,a6=0,a7=0;

      for (int i0 = s; i0 < e2; i0 += 64) {
        int navail = min(64, e2 - i0);
        unsigned ep = (lane < navail) ? epack[i0 + lane] : 0u;
        int c0 = 0;
        for (; c0 + 16 <= navail; c0 += 16) {
          unsigned ua = __shfl(ep, c0 + g);
          unsigned ub = __shfl(ep, c0 + 4 + g);
          unsigned uc = __shfl(ep, c0 + 8 + g);
          unsigned ud = __shfl(ep, c0 + 12 + g);
          uint4 ga = *(const uint4*)(xq + (size_t)(ua >> 16) * 64);
          uint4 gb = *(const uint4*)(xq + (size_t)(ub >> 16) * 64);
          uint4 gc = *(const uint4*)(xq + (size_t)(uc >> 16) * 64);
          uint4 gd = *(const uint4*)(xq + (size_t)(ud >> 16) * 64);
          float va = val16(ua), vb = val16(ub), vc = val16(uc), vd = val16(ud);
          ACC2(a0,a1,ga.x,va) ACC2(a2,a3,ga.y,va) ACC2(a4,a5,ga.z,va) ACC2(a6,a7,ga.w,va)
          ACC2(a0,a1,gb.x,vb) ACC2(a2,a3,gb.y,vb) ACC2(a4,a5,gb.z,vb) ACC2(a6,a7,gb.w,vb)
          ACC2(a0,a1,gc.x,vc) ACC2(a2,a3,gc.y,vc) ACC2(a4,a5,gc.z,vc) ACC2(a6,a7,gc.w,vc)
          ACC2(a0,a1,gd.x,vd) ACC2(a2,a3,gd.y,vd) ACC2(a4,a5,gd.z,vd) ACC2(a6,a7,gd.w,vd)
        }
        for (; c0 + 4 <= navail; c0 += 4) {
          unsigned u = __shfl(ep, c0 + g);
          uint4 gg = *(const uint4*)(xq + (size_t)(u >> 16) * 64);
          float v = val16(u);
          ACC2(a0,a1,gg.x,v) ACC2(a2,a3,gg.y,v) ACC2(a4,a5,gg.z,v) ACC2(a6,a7,gg.w,v)
        }
        if (c0 < navail) {
          int eidx = c0 + g;
          unsigned u = __shfl(ep, min(eidx, navail - 1));
          float v = (eidx < navail) ? val16(u) : 0.0f;
          uint4 gg = *(const uint4*)(xq + (size_t)(u >> 16) * 64);
          ACC2(a0,a1,gg.x,v) ACC2(a2,a3,gg.y,v) ACC2(a4,a5,gg.z,v) ACC2(a6,a7,gg.w,v)
        }
      }
      #define REDG(x) x += __shfl_xor(x, 16); x += __shfl_xor(x, 32);
      REDG(a0) REDG(a1) REDG(a2) REDG(a3) REDG(a4) REDG(a5) REDG(a6) REDG(a7)
      #undef REDG
      if (g == 0) {
        uint4 w;
        w.x = pack_bf2(a0, a1); w.y = pack_bf2(a2, a3);
        w.z = pack_bf2(a4, a5); w.w = pack_bf2(a6, a7);
        int slot = (r * 16 + q) ^ (row & 7);
        *(uint4*)(A_lds + row * 1024 + slot * 16) = w;
      }
      l0 += a0; l1 += a1; l2 += a2; l3 += a3;
      l4 += a4; l5 += a5; l6 += a6; l7 += a7;
    }

    // LayerNorm over the 128-dim summed slab
    float sum = l0+l1+l2+l3+l4+l5+l6+l7;
    float sq  = l0*l0+l1*l1+l2*l2+l3*l3+l4*l4+l5*l5+l6*l6+l7*l7;
    #pragma unroll
    for (int m = 1; m <= 8; m <<= 1) {
      sum += __shfl_xor(sum, m);
      sq  += __shfl_xor(sq,  m);
    }
    float mean = sum * (1.0f / D);
    float var  = sq * (1.0f / D) - mean * mean;
    float rstd = rsqrtf(var + EPS);
    float4 gm0 = *(const float4*)&gamma[8 * q];
    float4 gm1 = *(const float4*)&gamma[8 * q + 4];
    float4 bt0 = *(const float4*)&beta[8 * q];
    float4 bt1 = *(const float4*)&beta[8 * q + 4];
    float o0 = (l0 - mean) * rstd * gm0.x + bt0.x;
    float o1 = (l1 - mean) * rstd * gm0.y + bt0.y;
    float o2 = (l2 - mean) * rstd * gm0.z + bt0.z;
    float o3 = (l3 - mean) * rstd * gm0.w + bt0.w;
    float o4 = (l4 - mean) * rstd * gm1.x + bt1.x;
    float o5 = (l5 - mean) * rstd * gm1.y + bt1.y;
    float o6 = (l6 - mean) * rstd * gm1.z + bt1.z;
    float o7 = (l7 - mean) * rstd * gm1.w + bt1.w;
    if (g == 0) {
      uint4 w;
      w.x = pack_bf2(o0, o1); w.y = pack_bf2(o2, o3);
      w.z = pack_bf2(o4, o5); w.w = pack_bf2(o6, o7);
      int slot = (48 + q) ^ (row & 7);
      *(uint4*)(A_lds + row * 1024 + slot * 16) = w;
    }
  }
  __syncthreads();

  // ---- Phase 2: mini-GEMM [32 x 512] @ WT^T -> out rows n0..n0+31 ----
  // wave wv owns n-tiles {2wv, 2wv+1}; m-tiles 0,1 cover rows 0-15,16-31.
  f32x4 zero = {0.f, 0.f, 0.f, 0.f};
  f32x4 acc[2][2];
  acc[0][0] = zero; acc[0][1] = zero; acc[1][0] = zero; acc[1][1] = zero;
  int ks = lane >> 4;
  int lr = lane & 15;
  #pragma unroll
  for (int kk = 0; kk < 16; kk++) {
    bf16x8 af[2], bfr[2];
    #pragma unroll
    for (int m = 0; m < 2; m++) {
      int row = m * 16 + lr;
      int slot = (kk * 4 + ks) ^ (row & 7);
      af[m] = *(const bf16x8*)(A_lds + row * 1024 + slot * 16);
    }
    #pragma unroll
    for (int n = 0; n < 2; n++) {
      int col = (wv * 2 + n) * 16 + lr;
      bfr[n] = *(const bf16x8*)(WTb + (size_t)col * 1024 + kk * 64 + ks * 16);
    }
    #pragma unroll
    for (int m = 0; m < 2; m++)
      #pragma unroll
      for (int n = 0; n < 2; n++)
        acc[m][n] = __builtin_amdgcn_mfma_f32_16x16x32_bf16(
            af[m], bfr[n], acc[m][n], 0, 0, 0);
  }

  #pragma unroll
  for (int n = 0; n < 2; n++) {
    int col = (wv * 2 + n) * 16 + lr;
    float bv = bias[col];
    #pragma unroll
    for (int m = 0; m < 2; m++) {
      #pragma unroll
      for (int r = 0; r < 4; r++) {
        int row = m * 16 + (lane >> 4) * 4 + r;
        int node = n0 + row;
        if (node < NN) out[(size_t)node * 128 + col] = 0.5f * acc[m][n][r] + bv;
      }
    }
  }
}

// ---------------------------------------------------------------------------
extern "C" void kernel_launch(void* const* d_in, const int* in_sizes, int n_in,
                              void* d_out, int out_size, void* d_ws, size_t ws_size,
                              hipStream_t stream) {
  const float* input  = (const float*)d_in[0];
  const int*   arows  = (const int*)  d_in[1];
  const int*   acols  = (const int*)  d_in[2];
  const float* avals  = (const float*)d_in[3];
  const float* weight = (const float*)d_in[4];
  const float* shw    = (const float*)d_in[5];
  const float* bias   = (const float*)d_in[6];
  const float* gamma  = (const float*)d_in[7];
  const float* beta   = (const float*)d_in[8];
  float* out = (float*)d_out;

  char* ws = (char*)d_ws;
  unsigned short* WT = (unsigned short*)ws;  ws += (size_t)128 * 512 * 2;
  unsigned* xh  = (unsigned*)ws;             ws += (size_t)NN * 64 * 4;
  uint2* pedges = (uint2*)ws;                ws += (size_t)PART * CAP * sizeof(uint2);
  unsigned* epack = (unsigned*)ws;           ws += (size_t)NE * 4;
  int*   off   = (int*)ws;                   ws += ((size_t)RN + 4) * sizeof(int);
  int*   pcur  = (int*)ws;                   ws += (size_t)PART * sizeof(int);

  hipMemsetAsync(pcur, 0, (size_t)PART * sizeof(int), stream);
  prep        <<<NB_SPLIT + NB_XH + NB_WT, 256, 0, stream>>>(
                  arows, acols, avals, input, weight, shw, pcur, pedges, xh, WT);
  sort_part   <<<PART, 512, 0, stream>>>(pedges, pcur, off, epack);
  gather_gemm <<<(NN + NPB - 1) / NPB, 256, 0, stream>>>(
                  xh, epack, off, gamma, beta, (const char*)WT, bias, out);
}

// Round 18
// 168.222 us; speedup vs baseline: 1.2867x; 1.2867x over previous
//
#include <hip/hip_runtime.h>
#include <hip/hip_fp16.h>

// Problem constants (fixed by the reference)
constexpr int NN  = 50000;   // nodes
constexpr int NNZ = 800000;  // edges per relation
constexpr int RR  = 3;       // relations
constexpr int D   = 128;     // feature dim (in == out)
constexpr int RN  = RR * NN; // fine buckets (150000)
constexpr int NE  = RR * NNZ;
constexpr int KK  = 512;     // concat K: 3*128 support + 128 layernorm
constexpr int MPAD = 50048;  // 391 * 128, padded row count for A
constexpr int PART = 256;    // coarse partitions (1 sort block per CU)
constexpr int PSZ  = (RN + PART - 1) / PART;  // 586 buckets per partition
constexpr int CAP  = 10240;  // partition capacity (mean 9375, sd ~97)
constexpr int EPB  = 2048;   // edges per split block
constexpr float EPS = 1e-6f;

constexpr int NB_SPLIT = (NE + EPB - 1) / EPB;        // 1172
constexpr int NB_XH    = (NN * 64 + 255) / 256;       // 12500
constexpr int NB_WT    = 256;                         // 512*128 / 256

using bf16x8 = __attribute__((ext_vector_type(8))) __bf16;
using f32x4  = __attribute__((ext_vector_type(4))) float;

// RNE f32 -> bf16 packing helpers (NaN not possible here)
__device__ __forceinline__ unsigned pack_bf2(float a, float b) {
  unsigned ua = __float_as_uint(a); ua = (ua + (0x7FFFu + ((ua >> 16) & 1))) >> 16;
  unsigned ub = __float_as_uint(b); ub = (ub + (0x7FFFu + ((ub >> 16) & 1))) >> 16;
  return ua | (ub << 16);
}
__device__ __forceinline__ unsigned bf16_lo(float a) {
  unsigned ua = __float_as_uint(a);
  return (ua + (0x7FFFu + ((ua >> 16) & 1))) >> 16;
}

__device__ __forceinline__ void gload16(const void* g, void* l) {
  __builtin_amdgcn_global_load_lds(
      (const __attribute__((address_space(1))) unsigned int*)g,
      (__attribute__((address_space(3))) unsigned int*)l, 16, 0, 0);
}

__device__ __forceinline__ float val16(unsigned u) {
  return __half2float(__ushort_as_half((unsigned short)(u & 0xFFFFu)));
}

// fp16-pair FMA into f32 accumulators
#define ACC2(accA, accB, word, vv) {                                   \
    __half2 _h = __builtin_bit_cast(__half2, (word));                  \
    accA = __builtin_fmaf(__half2float(_h.x), (vv), accA);             \
    accB = __builtin_fmaf(__half2float(_h.y), (vv), accB); }

// ---------------------------------------------------------------------------
// K1 "prep": compact multisplit + table builds fused.
// Blocks [0,NB_SPLIT): edge multisplit (histogram -> scan -> compact sbuf ->
// dense flush). 20KB LDS -> 8 blocks/CU, so the copy blocks that share the
// dispatch run at FULL occupancy. Next NB_XH blocks: x -> fp16 pair table.
// Last NB_WT: W^T bf16.
// ---------------------------------------------------------------------------
__global__ __launch_bounds__(256) void prep(
    const int*   __restrict__ rows,
    const int*   __restrict__ cols,
    const float* __restrict__ vals,
    const float* __restrict__ x,
    const float* __restrict__ w,     // [384][128]
    const float* __restrict__ shw,   // [128][128]
    int*   __restrict__ pcur,        // [PART]
    uint2* __restrict__ pedges,      // [PART*CAP]
    unsigned* __restrict__ xh,       // [NN*64] half2
    unsigned short* __restrict__ WT) { // bf16 [128][512]
  __shared__ uint2 sbuf[EPB];        // 16 KB compact staging
  __shared__ int lcur[PART];         // counts -> cursors
  __shared__ int lstart[PART];       // block-local exclusive prefix
  __shared__ int lbase[PART];        // global base within partition
  __shared__ int sdata[256];
  int blk = blockIdx.x;
  int t = threadIdx.x;

  if (blk >= NB_SPLIT) {                     // ---- copy paths (no LDS use)
    int b2 = blk - NB_SPLIT;
    if (b2 < NB_XH) {                        // build_xh
      int i = b2 * 256 + t;
      float2 v = ((const float2*)x)[i];
      xh[i] = __builtin_bit_cast(unsigned, __floats2half2_rn(v.x, v.y));
    } else {                                 // build_wt
      int idx = (b2 - NB_XH) * 256 + t;      // 0..65535
      int k   = idx >> 7;
      int col = idx & 127;
      float v = (k < 384) ? w[k * 128 + col] : shw[(k - 384) * 128 + col];
      WT[col * 512 + k] = (unsigned short)bf16_lo(v);
    }
    return;
  }

  // ---- multisplit path
  lcur[t] = 0;
  __syncthreads();

  int e0 = blk * EPB;
  int nvalid = min(EPB, NE - e0);
  constexpr int EPT = EPB / 256;     // 8 edges per thread
  int ebk[EPT]; unsigned epay[EPT];
  #pragma unroll
  for (int j = 0; j < EPT; j++) {
    int e = e0 + j * 256 + t;
    if (e < NE) {
      int r = (e >= 2 * NNZ) ? 2 : (e >= NNZ ? 1 : 0);
      int b = r * NN + rows[e];
      ebk[j] = b;
      epay[j] = ((unsigned)cols[e] << 16) |
                (unsigned)__half_as_ushort(__float2half_rn(vals[e]));
      atomicAdd(&lcur[b / PSZ], 1);
    } else {
      ebk[j] = -1;
    }
  }
  __syncthreads();

  // block-exclusive scan of the 256 counts; grab global bases
  int cnt = lcur[t];
  sdata[t] = cnt;
  __syncthreads();
  #pragma unroll
  for (int step = 1; step < 256; step <<= 1) {
    int v = (t >= step) ? sdata[t - step] : 0;
    __syncthreads();
    sdata[t] += v;
    __syncthreads();
  }
  int excl = sdata[t] - cnt;
  lstart[t] = excl;
  lbase[t] = atomicAdd(&pcur[t], cnt);
  __syncthreads();
  lcur[t] = excl;                    // reuse as placement cursor
  __syncthreads();

  // place edges at exact flat ranks (compact, no overflow possible)
  #pragma unroll
  for (int j = 0; j < EPT; j++) {
    if (ebk[j] >= 0) {
      int pos = atomicAdd(&lcur[ebk[j] / PSZ], 1);
      sbuf[pos] = make_uint2((unsigned)ebk[j], epay[j]);
    }
  }
  __syncthreads();

  // dense flush: consecutive threads -> consecutive sbuf entries -> runs of
  // same partition -> coalesced stores. partition recomputed by magic-div.
  for (int i = t; i < nvalid; i += 256) {
    uint2 ed = sbuf[i];
    int p = (int)(ed.x / PSZ);
    pedges[(size_t)p * CAP + lbase[p] + (i - lstart[p])] = ed;
  }
}

// ---------------------------------------------------------------------------
// K2: per-partition LDS counting sort (256 blocks x 512 threads). Inlines
// the partition prefix (tree-reduce of pcur[0..p)).
// ---------------------------------------------------------------------------
__global__ __launch_bounds__(512) void sort_part(
    const uint2* __restrict__ pedges,
    const int*   __restrict__ pcur,
    int* __restrict__ off,
    unsigned* __restrict__ epack) {
  __shared__ int sc[PSZ];
  __shared__ int sdata[512];
  int p = blockIdx.x;
  int t = threadIdx.x;
  int bb = p * PSZ;
  int nbuck = min(PSZ, RN - bb);
  int n = pcur[p];
  const uint2* src = pedges + (size_t)p * CAP;

  // gbase = sum_{i<p} pcur[i]
  sdata[t] = (t < p && t < PART) ? pcur[t] : 0;
  __syncthreads();
  #pragma unroll
  for (int step = 256; step >= 1; step >>= 1) {
    if (t < step) sdata[t] += sdata[t + step];
    __syncthreads();
  }
  int gbase = sdata[0];
  __syncthreads();
  if (p == 0 && t == 0) off[RN] = NE;

  for (int i = t; i < nbuck; i += 512) sc[i] = 0;
  __syncthreads();
  for (int i = t; i < n; i += 512)
    atomicAdd(&sc[src[i].x - bb], 1);
  __syncthreads();

  constexpr int PER = (PSZ + 511) / 512;    // 2
  int lo = t * PER, hi = min(lo + PER, nbuck);
  int s = 0;
  for (int i = lo; i < hi; i++) s += sc[i];
  sdata[t] = s;
  __syncthreads();
  #pragma unroll
  for (int step = 1; step < 512; step <<= 1) {
    int v = (t >= step) ? sdata[t - step] : 0;
    __syncthreads();
    sdata[t] += v;
    __syncthreads();
  }
  int run = gbase + sdata[t] - s;
  for (int i = lo; i < hi; i++) {
    int c = sc[i];
    sc[i] = run;
    off[bb + i] = run;
    run += c;
  }
  __syncthreads();

  for (int i = t; i < n; i += 512) {
    uint2 ed = src[i];
    int pos = atomicAdd(&sc[ed.x - bb], 1);
    epack[pos] = ed.y;
  }
}

// ---------------------------------------------------------------------------
// K3: gather SpMM (3 relations) + sum + LayerNorm, fused (R11 body).
// 16 lanes per edge (4 edge-groups); lane q owns dims 8q..8q+7 (one dwordx4).
// Structurally floored at ~80us by the gather memory path (R8/R9/R10/R12/R16
// variants all neutral-or-worse).
// ---------------------------------------------------------------------------
__global__ __launch_bounds__(256) void gather_ln(
    const unsigned* __restrict__ xh,    // [NN][64] half2
    const unsigned* __restrict__ epack, // [NE] col16|fp16val, bucket-sorted
    const int*      __restrict__ off,   // [RN+1]
    const float* __restrict__ gamma,
    const float* __restrict__ beta,
    unsigned* __restrict__ Au) {        // A as uint view: [MPAD][256]
  int node = blockIdx.x * 4 + (threadIdx.x >> 6);
  if (node >= NN) return;
  int lane = threadIdx.x & 63;
  int g  = lane >> 4;        // edge subgroup 0..3
  int q  = lane & 15;        // dim slice: dims 8q..8q+7
  const unsigned* xq = xh + q * 4;

  float l0=0,l1=0,l2=0,l3=0,l4=0,l5=0,l6=0,l7=0;   // LN accumulator (sum slabs)

  #pragma unroll
  for (int r = 0; r < RR; r++) {
    int b = r * NN + node;
    int s = off[b], e2 = off[b + 1];
    float a0=0,a1=0,a2=0,a3=0,a4=0,a5=0,a6=0,a7=0; // this lane, group-g edges

    for (int i0 = s; i0 < e2; i0 += 64) {
      int navail = min(64, e2 - i0);
      unsigned ep = (lane < navail) ? epack[i0 + lane] : 0u;
      int c0 = 0;
      // main: 16 edges (4 per group) per iteration, 4 gathers in flight
      for (; c0 + 16 <= navail; c0 += 16) {
        unsigned ua = __shfl(ep, c0 + g);
        unsigned ub = __shfl(ep, c0 + 4 + g);
        unsigned uc = __shfl(ep, c0 + 8 + g);
        unsigned ud = __shfl(ep, c0 + 12 + g);
        uint4 ga = *(const uint4*)(xq + (size_t)(ua >> 16) * 64);
        uint4 gb = *(const uint4*)(xq + (size_t)(ub >> 16) * 64);
        uint4 gc = *(const uint4*)(xq + (size_t)(uc >> 16) * 64);
        uint4 gd = *(const uint4*)(xq + (size_t)(ud >> 16) * 64);
        float va = val16(ua), vb = val16(ub), vc = val16(uc), vd = val16(ud);
        ACC2(a0,a1,ga.x,va) ACC2(a2,a3,ga.y,va) ACC2(a4,a5,ga.z,va) ACC2(a6,a7,ga.w,va)
        ACC2(a0,a1,gb.x,vb) ACC2(a2,a3,gb.y,vb) ACC2(a4,a5,gb.z,vb) ACC2(a6,a7,gb.w,vb)
        ACC2(a0,a1,gc.x,vc) ACC2(a2,a3,gc.y,vc) ACC2(a4,a5,gc.z,vc) ACC2(a6,a7,gc.w,vc)
        ACC2(a0,a1,gd.x,vd) ACC2(a2,a3,gd.y,vd) ACC2(a4,a5,gd.z,vd) ACC2(a6,a7,gd.w,vd)
      }
      // full 4-edge chunks
      for (; c0 + 4 <= navail; c0 += 4) {
        unsigned u = __shfl(ep, c0 + g);
        uint4 gg = *(const uint4*)(xq + (size_t)(u >> 16) * 64);
        float v = val16(u);
        ACC2(a0,a1,gg.x,v) ACC2(a2,a3,gg.y,v) ACC2(a4,a5,gg.z,v) ACC2(a6,a7,gg.w,v)
      }
      // ragged tail (<=1 step): invalid groups contribute v=0
      if (c0 < navail) {
        int eidx = c0 + g;
        unsigned u = __shfl(ep, min(eidx, navail - 1));
        float v = (eidx < navail) ? val16(u) : 0.0f;
        uint4 gg = *(const uint4*)(xq + (size_t)(u >> 16) * 64);
        ACC2(a0,a1,gg.x,v) ACC2(a2,a3,gg.y,v) ACC2(a4,a5,gg.z,v) ACC2(a6,a7,gg.w,v)
      }
    }
    // combine the 4 edge-groups
    #define REDG(x) x += __shfl_xor(x, 16); x += __shfl_xor(x, 32);
    REDG(a0) REDG(a1) REDG(a2) REDG(a3) REDG(a4) REDG(a5) REDG(a6) REDG(a7)
    #undef REDG
    if (g == 0) {
      uint4 w;
      w.x = pack_bf2(a0, a1); w.y = pack_bf2(a2, a3);
      w.z = pack_bf2(a4, a5); w.w = pack_bf2(a6, a7);
      *(uint4*)(Au + (size_t)node * 256 + r * 64 + q * 4) = w;
    }
    l0 += a0; l1 += a1; l2 += a2; l3 += a3;
    l4 += a4; l5 += a5; l6 += a6; l7 += a7;
  }

  // LayerNorm over the 128-dim summed slab
  float sum = l0+l1+l2+l3+l4+l5+l6+l7;
  float sq  = l0*l0+l1*l1+l2*l2+l3*l3+l4*l4+l5*l5+l6*l6+l7*l7;
  #pragma unroll
  for (int m = 1; m <= 8; m <<= 1) {
    sum += __shfl_xor(sum, m);
    sq  += __shfl_xor(sq,  m);
  }
  float mean = sum * (1.0f / D);
  float var  = sq * (1.0f / D) - mean * mean;
  float rstd = rsqrtf(var + EPS);
  float4 gm0 = *(const float4*)&gamma[8 * q];
  float4 gm1 = *(const float4*)&gamma[8 * q + 4];
  float4 bt0 = *(const float4*)&beta[8 * q];
  float4 bt1 = *(const float4*)&beta[8 * q + 4];
  float o0 = (l0 - mean) * rstd * gm0.x + bt0.x;
  float o1 = (l1 - mean) * rstd * gm0.y + bt0.y;
  float o2 = (l2 - mean) * rstd * gm0.z + bt0.z;
  float o3 = (l3 - mean) * rstd * gm0.w + bt0.w;
  float o4 = (l4 - mean) * rstd * gm1.x + bt1.x;
  float o5 = (l5 - mean) * rstd * gm1.y + bt1.y;
  float o6 = (l6 - mean) * rstd * gm1.z + bt1.z;
  float o7 = (l7 - mean) * rstd * gm1.w + bt1.w;
  if (g == 0) {
    uint4 w;
    w.x = pack_bf2(o0, o1); w.y = pack_bf2(o2, o3);
    w.z = pack_bf2(o4, o5); w.w = pack_bf2(o6, o7);
    *(uint4*)(Au + (size_t)node * 256 + 192 + q * 4) = w;
  }
}

// ---------------------------------------------------------------------------
// K4: bf16 MFMA GEMM.  out = 0.5 * A[50000][512] @ W[512][128] + bias
// BM=128, BN=128, BK=64. 512 threads = 8 waves (4x2).
// ---------------------------------------------------------------------------
__global__ __launch_bounds__(512) void gemm_mfma(
    const char* __restrict__ Ab,    // bf16 [MPAD][512] as bytes
    const char* __restrict__ Bb,    // bf16 [128][512] (W^T) as bytes
    const float* __restrict__ bias, // [128]
    float* __restrict__ out) {      // [NN][128]
  __shared__ __align__(16) char smem[32768];   // As 16KB | Bs 16KB
  char* As = smem;
  char* Bs = smem + 16384;

  int tid  = threadIdx.x;
  int wid  = tid >> 6;
  int lane = tid & 63;
  int wr   = wid >> 1;
  int wc   = wid & 1;
  int row0 = blockIdx.x * 128;

  f32x4 zero = {0.f, 0.f, 0.f, 0.f};
  f32x4 acc[2][4];
  #pragma unroll
  for (int i = 0; i < 2; i++)
    #pragma unroll
    for (int j = 0; j < 4; j++) acc[i][j] = zero;

  for (int kc = 0; kc < 8; kc++) {
    #pragma unroll
    for (int i = 0; i < 2; i++) {
      int c = i * 512 + tid;
      int r = c >> 3, s = c & 7;
      int ss = s ^ (r & 7);
      const void* src = Ab + (size_t)(row0 + r) * 1024 + kc * 128 + ss * 16;
      void* dst = As + i * 8192 + wid * 1024;
      gload16(src, dst);
    }
    #pragma unroll
    for (int i = 0; i < 2; i++) {
      int c = i * 512 + tid;
      int r = c >> 3, s = c & 7;
      int ss = s ^ (r & 7);
      const void* src = Bb + (size_t)r * 1024 + kc * 128 + ss * 16;
      void* dst = Bs + i * 8192 + wid * 1024;
      gload16(src, dst);
    }
    __syncthreads();

    #pragma unroll
    for (int ks = 0; ks < 2; ks++) {
      bf16x8 afrag[2], bfrag[4];
      int sg = ks * 4 + (lane >> 4);
      #pragma unroll
      for (int rb = 0; rb < 2; rb++) {
        int r = wr * 32 + rb * 16 + (lane & 15);
        afrag[rb] = *(const bf16x8*)(As + r * 128 + (sg ^ (r & 7)) * 16);
      }
      #pragma unroll
      for (int cb = 0; cb < 4; cb++) {
        int col = wc * 64 + cb * 16 + (lane & 15);
        bfrag[cb] = *(const bf16x8*)(Bs + col * 128 + (sg ^ (col & 7)) * 16);
      }
      #pragma unroll
      for (int rb = 0; rb < 2; rb++)
        #pragma unroll
        for (int cb = 0; cb < 4; cb++)
          acc[rb][cb] = __builtin_amdgcn_mfma_f32_16x16x32_bf16(
              afrag[rb], bfrag[cb], acc[rb][cb], 0, 0, 0);
    }
    __syncthreads();
  }

  #pragma unroll
  for (int rb = 0; rb < 2; rb++) {
    #pragma unroll
    for (int cb = 0; cb < 4; cb++) {
      int col = wc * 64 + cb * 16 + (lane & 15);
      float bv = bias[col];
      #pragma unroll
      for (int r = 0; r < 4; r++) {
        int grow = row0 + wr * 32 + rb * 16 + (lane >> 4) * 4 + r;
        if (grow < NN) out[(size_t)grow * 128 + col] = 0.5f * acc[rb][cb][r] + bv;
      }
    }
  }
}

// ---------------------------------------------------------------------------
extern "C" void kernel_launch(void* const* d_in, const int* in_sizes, int n_in,
                              void* d_out, int out_size, void* d_ws, size_t ws_size,
                              hipStream_t stream) {
  const float* input  = (const float*)d_in[0];
  const int*   arows  = (const int*)  d_in[1];
  const int*   acols  = (const int*)  d_in[2];
  const float* avals  = (const float*)d_in[3];
  const float* weight = (const float*)d_in[4];
  const float* shw    = (const float*)d_in[5];
  const float* bias   = (const float*)d_in[6];
  const float* gamma  = (const float*)d_in[7];
  const float* beta   = (const float*)d_in[8];
  float* out = (float*)d_out;

  char* ws = (char*)d_ws;
  char*  Abf   = ws;                         ws += (size_t)MPAD * KK * 2;
  unsigned short* WT = (unsigned short*)ws;  ws += (size_t)128 * KK * 2;
  unsigned* xh  = (unsigned*)ws;             ws += (size_t)NN * 64 * 4;
  uint2* pedges = (uint2*)ws;                ws += (size_t)PART * CAP * sizeof(uint2);
  unsigned* epack = (unsigned*)ws;           ws += (size_t)NE * 4;
  int*   off   = (int*)ws;                   ws += ((size_t)RN + 4) * sizeof(int);
  int*   pcur  = (int*)ws;                   ws += (size_t)PART * sizeof(int);

  hipMemsetAsync(pcur, 0, (size_t)PART * sizeof(int), stream);
  prep      <<<NB_SPLIT + NB_XH + NB_WT, 256, 0, stream>>>(
                arows, acols, avals, input, weight, shw, pcur, pedges, xh, WT);
  sort_part <<<PART, 512, 0, stream>>>(pedges, pcur, off, epack);
  gather_ln <<<(NN + 3) / 4, 256, 0, stream>>>(xh, epack, off, gamma, beta,
                                               (unsigned*)Abf);
  gemm_mfma <<<MPAD / 128, 512, 0, stream>>>(Abf, (const char*)WT, bias, out);
}